// Round 8
// baseline (467.044 us; speedup 1.0000x reference)
//
#include <hip/hip_runtime.h>
#include <cmath>

#define B_ROWS 16384
#define E_DIM 512
#define H_DIM 1024
#define P_DIM 256
#define K1_RAW 1026
#define K1_PAD 1088   // multiple of 64

#define NEG_BIG (-3.0e38f)
#define SCL_IN  16.0f            // fp8 pre-scale for A1 and all weights
#define INV_G1  (1.0f / 256.0f)  // GEMM1: A(x16) * W(x16)
#define INV_G   (1.0f / 16.0f)   // GEMM2-4: A(x1) * W(x16)

typedef __attribute__((ext_vector_type(4))) short short4v;
typedef __attribute__((ext_vector_type(8))) short short8v;
typedef __attribute__((ext_vector_type(4))) float f32x4;
typedef __attribute__((ext_vector_type(2))) long long2v;

__device__ __forceinline__ short f2bf(float f) {
    unsigned u = __float_as_uint(f);
    u += 0x7fffu + ((u >> 16) & 1u);   // round-to-nearest-even
    return (short)(u >> 16);
}
__device__ __forceinline__ float bf2f(short s) {
    return __uint_as_float(((unsigned)(unsigned short)s) << 16);
}
// pack 4 floats -> 4 OCP e4m3 bytes (HW cvt, RNE+sat)
__device__ __forceinline__ int pk4_fp8(float a, float b, float c, float d) {
    int v = __builtin_amdgcn_cvt_pk_fp8_f32(a, b, 0, false);
    return  __builtin_amdgcn_cvt_pk_fp8_f32(c, d, v, true);
}

// K-interleave permutation: within each 64-k block, store the 8 eight-byte
// MFMA quad-chunks as [A0 B0 A1 B1 A2 B2 A3 B3] so a single b128 read at
// quad*16 returns {k-step0 frag, k-step1 frag} for mfma_16x16x32_fp8_fp8.
__device__ __forceinline__ int kperm(int k) {
    return (k & ~63) | (((k >> 3) & 3) << 4) | (((k >> 5) & 1) << 3) | (k & 7);
}

// ---------------------------------------------------------------------------
// prep_a1: per-row L2 norms + emit fp8 A1[b][1088] (K-interleaved) =
// 16*[x1*inv1 | x2*inv2 | gf | 0pad]
__global__ __launch_bounds__(256) void prep_a1(
    const float* __restrict__ x1, const float* __restrict__ x2,
    const float* __restrict__ gf, char* __restrict__ A1)
{
    const int b = blockIdx.x;
    const int t = threadIdx.x;
    __shared__ float red[4];

    const float* src = (t < 128) ? x1 : x2;
    const int idx = (t & 127) << 2;
    float4 v = *(const float4*)&src[(size_t)b * E_DIM + idx];
    float ss = v.x*v.x + v.y*v.y + v.z*v.z + v.w*v.w;
    #pragma unroll
    for (int off = 32; off > 0; off >>= 1) ss += __shfl_xor(ss, off, 64);
    if ((t & 63) == 0) red[t >> 6] = ss;
    __syncthreads();
    const float inv1 = SCL_IN / fmaxf(sqrtf(red[0] + red[1]), 1e-12f);
    const float inv2 = SCL_IN / fmaxf(sqrtf(red[2] + red[3]), 1e-12f);

    const size_t rb = (size_t)b * K1_PAD;
    {
        const int k = t << 2;   // 0..1020
        const float* s = (k < E_DIM) ? &x1[(size_t)b * E_DIM + k]
                                     : &x2[(size_t)b * E_DIM + k - E_DIM];
        const float iv = (k < E_DIM) ? inv1 : inv2;
        float4 u = *(const float4*)s;
        *(int*)&A1[rb + kperm(k)] = pk4_fp8(u.x * iv, u.y * iv, u.z * iv, u.w * iv);
    }
    if (t < 16) {
        const int k = 1024 + (t << 2);   // 1024..1084, covers full pad block
        float vals[4];
        #pragma unroll
        for (int i = 0; i < 4; ++i) {
            int kk = k + i;
            vals[i] = (kk == 1024) ? gf[(size_t)b * 2 + 0] * SCL_IN
                    : (kk == 1025) ? gf[(size_t)b * 2 + 1] * SCL_IN : 0.f;
        }
        *(int*)&A1[rb + kperm(k)] = pk4_fp8(vals[0], vals[1], vals[2], vals[3]);
    }
}

// ---------------------------------------------------------------------------
// transpose_cvt_all: W fp32 [K][N] -> Wt fp8 [N][Kpad] (K-interleaved, x16).
__global__ __launch_bounds__(256) void transpose_cvt_all(
    const float* __restrict__ W0, char* __restrict__ Wt0,   // 1026->1088 x1024
    const float* __restrict__ W1, char* __restrict__ Wt1,   // 1024x1024
    const float* __restrict__ W2, char* __restrict__ Wt2,   // 1024x1024
    const float* __restrict__ W3, char* __restrict__ Wt3)   // 1024x256
{
    const int z = blockIdx.z;
    const float* W; char* Wt; int K, N, Kpad;
    if (z == 0)      { W = W0; Wt = Wt0; K = K1_RAW; N = H_DIM; Kpad = K1_PAD; }
    else if (z == 1) { W = W1; Wt = Wt1; K = H_DIM;  N = H_DIM; Kpad = H_DIM; }
    else if (z == 2) { W = W2; Wt = Wt2; K = H_DIM;  N = H_DIM; Kpad = H_DIM; }
    else             { W = W3; Wt = Wt3; K = H_DIM;  N = P_DIM; Kpad = H_DIM; }

    const int k0 = blockIdx.x * 64, n0 = blockIdx.y * 64;
    if (k0 >= Kpad || n0 >= N) return;

    __shared__ float T[64][68];
    const int t = threadIdx.x;
    const int r = t >> 4;          // 0..15
    const int c = (t & 15) << 2;   // 0..60
    #pragma unroll
    for (int rr = 0; rr < 4; ++rr) {
        int k = k0 + r + rr * 16;
        float4 v = (k < K) ? *(const float4*)&W[(size_t)k * N + n0 + c]
                           : make_float4(0.f, 0.f, 0.f, 0.f);
        v.x *= SCL_IN; v.y *= SCL_IN; v.z *= SCL_IN; v.w *= SCL_IN;
        *(float4*)&T[r + rr * 16][c] = v;
    }
    __syncthreads();
    const int n = n0 + (t >> 2);
    const int cn = t >> 2;
    const int ks = (t & 3) << 4;   // 0,16,32,48
    #pragma unroll
    for (int g = 0; g < 2; ++g) {
        int kk = ks + g * 8;       // 0,8,...,56
        int k = k0 + kk;
        if (k + 7 < Kpad) {
            int lo = pk4_fp8(T[kk+0][cn], T[kk+1][cn], T[kk+2][cn], T[kk+3][cn]);
            int hi = pk4_fp8(T[kk+4][cn], T[kk+5][cn], T[kk+6][cn], T[kk+7][cn]);
            int2 o = { lo, hi };
            int np = k0 + (((kk >> 3) & 3) << 4) + (((kk >> 5) & 1) << 3);
            *(int2*)&Wt[(size_t)n * Kpad + np] = o;
        }
    }
}

// ---------------------------------------------------------------------------
// gemm_f8: C[M,N] = A[M,KA](fp8,K-ilv) @ Bt[N,KA]^T(fp8,K-ilv)*cscale + bias.
// NO LDS, NO barriers in the K-loop: both operands are cache-hot (B strip
// 128 KB in L2, A 17 MB in Infinity Cache), so fragments load per-lane
// straight from global (each wave b128 covers 16 rows x 64 B, coalesced).
// KA is a template constant -> fully unrolled K-loop -> compiler software-
// pipelines loads against MFMAs with fine-grained vmcnt (AITER pattern).
// LDS is used only for a coalesced C epilogue.
template <int BF16OUT, int KA>
__global__ __launch_bounds__(256) void gemm_f8(
    const char* __restrict__ A, const char* __restrict__ Bt,
    const float* __restrict__ bias, float cscale, float* __restrict__ Cf,
    short* __restrict__ Cb, int N)
{
    constexpr int NK = KA >> 6;
    __shared__ __align__(16) char csmem[BF16OUT ? 128 * 132 * 2 : 128 * 132 * 4];

    const int t = threadIdx.x;
    const int w = t >> 6, lane = t & 63;
    const int wm = w & 1, wn = w >> 1;
    const int m16 = lane & 15, quad = lane >> 4;
    const int row0 = blockIdx.x * 128, col0 = blockIdx.y * 128;

    const char* Ap = A  + (size_t)(row0 + wm * 64 + m16) * KA + quad * 16;
    const char* Bp = Bt + (size_t)(col0 + wn * 64 + m16) * KA + quad * 16;

    f32x4 acc[4][4];
    #pragma unroll
    for (int i = 0; i < 4; ++i)
        #pragma unroll
        for (int j = 0; j < 4; ++j)
            acc[i][j] = (f32x4){0.f, 0.f, 0.f, 0.f};

    #pragma unroll
    for (int kt = 0; kt < NK; ++kt) {
        long2v a2[4], b2[4];
        #pragma unroll
        for (int i = 0; i < 4; ++i)
            a2[i] = *(const long2v*)(Ap + (size_t)(i * 16) * KA + kt * 64);
        #pragma unroll
        for (int j = 0; j < 4; ++j)
            b2[j] = *(const long2v*)(Bp + (size_t)(j * 16) * KA + kt * 64);
        #pragma unroll
        for (int i = 0; i < 4; ++i)
            #pragma unroll
            for (int j = 0; j < 4; ++j) {
                acc[i][j] = __builtin_amdgcn_mfma_f32_16x16x32_fp8_fp8(
                    a2[i][0], b2[j][0], acc[i][j], 0, 0, 0);
                acc[i][j] = __builtin_amdgcn_mfma_f32_16x16x32_fp8_fp8(
                    a2[i][1], b2[j][1], acc[i][j], 0, 0, 0);
            }
    }

    // ---- coalesced epilogue via LDS ----
    // acc layout: row = quad*4 + r, col = m16 per 16x16 tile
    if (BF16OUT) {
        short* Cs = (short*)csmem;   // [128][132]
        #pragma unroll
        for (int j = 0; j < 4; ++j) {
            const int col = wn * 64 + j * 16 + m16;
            const float bj = bias[col0 + col];
            #pragma unroll
            for (int i = 0; i < 4; ++i) {
                const int rbase = wm * 64 + i * 16 + quad * 4;
                #pragma unroll
                for (int r = 0; r < 4; ++r)
                    Cs[(rbase + r) * 132 + col] = f2bf(acc[i][j][r] * cscale + bj);
            }
        }
        __syncthreads();
        const int row = t >> 1, half = t & 1;
        #pragma unroll
        for (int c8 = 0; c8 < 4; ++c8) {
            short8v v = *(const short8v*)&Cs[row * 132 + half * 64 + c8 * 8];
            *(short8v*)&Cb[(size_t)(row0 + row) * N + col0 + half * 64 + c8 * 8] = v;
        }
    } else {
        float* Cs = (float*)csmem;   // [128][132]
        #pragma unroll
        for (int j = 0; j < 4; ++j) {
            const int col = wn * 64 + j * 16 + m16;
            const float bj = bias[col0 + col];
            #pragma unroll
            for (int i = 0; i < 4; ++i) {
                const int rbase = wm * 64 + i * 16 + quad * 4;
                #pragma unroll
                for (int r = 0; r < 4; ++r)
                    Cs[(rbase + r) * 132 + col] = acc[i][j][r] * cscale + bj;
            }
        }
        __syncthreads();
        const int row = t >> 1, half = t & 1;
        #pragma unroll
        for (int c4 = 0; c4 < 16; ++c4) {
            float4 v = *(const float4*)&Cs[row * 132 + half * 64 + c4 * 4];
            *(float4*)&Cf[(size_t)(row0 + row) * N + col0 + half * 64 + c4 * 4] = v;
        }
    }
}

// ---------------------------------------------------------------------------
__device__ __forceinline__ void block_reduce2(float& s, float& ss)
{
    __shared__ float red[2][4];
    #pragma unroll
    for (int off = 32; off > 0; off >>= 1) {
        s  += __shfl_xor(s,  off, 64);
        ss += __shfl_xor(ss, off, 64);
    }
    int lane = threadIdx.x & 63, w = threadIdx.x >> 6;
    if (lane == 0) { red[0][w] = s; red[1][w] = ss; }
    __syncthreads();
    if (threadIdx.x == 0) {
        red[0][0] = red[0][0] + red[0][1] + red[0][2] + red[0][3];
        red[1][0] = red[1][0] + red[1][1] + red[1][2] + red[1][3];
    }
    __syncthreads();
    s = red[0][0]; ss = red[1][0];
}

// LN+ReLU over bf16 GEMM out (+bf16 residual). Writes fp8 act (K-interleaved)
// and optionally bf16 running residual.
template <int HAS_RES, int WRITE_BF>
__global__ __launch_bounds__(256) void ln_relu_f8(
    const short* __restrict__ X, const float* __restrict__ gamma,
    const float* __restrict__ beta, const short* __restrict__ res,
    char* __restrict__ act, short* __restrict__ resout)
{
    const int row = blockIdx.x;
    const size_t base = (size_t)row * H_DIM;
    const int idx = threadIdx.x << 2;
    short4v xb = *(const short4v*)&X[base + idx];
    float4 x = { bf2f(xb[0]), bf2f(xb[1]), bf2f(xb[2]), bf2f(xb[3]) };
    float s  = x.x + x.y + x.z + x.w;
    float ss = x.x*x.x + x.y*x.y + x.z*x.z + x.w*x.w;
    block_reduce2(s, ss);
    float m = s * (1.f / H_DIM);
    float var = fmaxf(ss * (1.f / H_DIM) - m * m, 0.f);
    float r = 1.f / sqrtf(var + 1e-5f);
    float4 g  = *(const float4*)&gamma[idx];
    float4 be = *(const float4*)&beta[idx];
    float4 y;
    y.x = fmaxf((x.x - m) * r * g.x + be.x, 0.f);
    y.y = fmaxf((x.y - m) * r * g.y + be.y, 0.f);
    y.z = fmaxf((x.z - m) * r * g.z + be.z, 0.f);
    y.w = fmaxf((x.w - m) * r * g.w + be.w, 0.f);
    if (HAS_RES) {
        short4v rr = *(const short4v*)&res[base + idx];
        y.x += bf2f(rr[0]); y.y += bf2f(rr[1]); y.z += bf2f(rr[2]); y.w += bf2f(rr[3]);
    }
    *(int*)&act[base + kperm(idx)] = pk4_fp8(y.x, y.y, y.z, y.w);
    if (WRITE_BF) {
        short4v o = { f2bf(y.x), f2bf(y.y), f2bf(y.z), f2bf(y.w) };
        *(short4v*)&resout[base + idx] = o;
    }
}

// ---------------------------------------------------------------------------
// fused final LN (H=256, fp32 in) + classifier + gender mask
__global__ __launch_bounds__(256) void ln_cls(
    const float* __restrict__ X, const float* __restrict__ gamma,
    const float* __restrict__ beta, const float* __restrict__ Wc,
    const float* __restrict__ bc, const float* __restrict__ gf,
    float* __restrict__ out)
{
    const int row = blockIdx.x;
    const size_t base = (size_t)row * P_DIM;
    const int t = threadIdx.x;
    float x = X[base + t];
    float s = x, ss = x * x;
    block_reduce2(s, ss);
    float m = s * (1.f / P_DIM);
    float var = fmaxf(ss * (1.f / P_DIM) - m * m, 0.f);
    float r = 1.f / sqrtf(var + 1e-5f);
    float y = fmaxf((x - m) * r * gamma[t] + beta[t], 0.f);

    __shared__ float part[4][8];
    const int lane = t & 63, w = t >> 6;
    #pragma unroll
    for (int c = 0; c < 7; ++c) {
        float v = y * Wc[t * 7 + c];
        #pragma unroll
        for (int off = 32; off > 0; off >>= 1) v += __shfl_xor(v, off, 64);
        if (lane == 0) part[w][c] = v;
    }
    __syncthreads();
    if (t < 7) {
        float v = part[0][t] + part[1][t] + part[2][t] + part[3][t] + bc[t];
        int g1 = (gf[(size_t)row * 2 + 0] != 0.f);
        int g2 = (gf[(size_t)row * 2 + 1] != 0.f);
        unsigned bits = (g1 == g2) ? (g1 ? 0x24u : 0x12u) : 0x49u;
        out[(size_t)row * 7 + t] = ((bits >> t) & 1u) ? v : NEG_BIG;
    }
}

// ---------------------------------------------------------------------------
extern "C" void kernel_launch(void* const* d_in, const int* in_sizes, int n_in,
                              void* d_out, int out_size, void* d_ws, size_t ws_size,
                              hipStream_t stream)
{
    const float* x1   = (const float*)d_in[0];
    const float* x2   = (const float*)d_in[1];
    const float* gf   = (const float*)d_in[2];
    const float* W_in = (const float*)d_in[3];
    const float* b_in = (const float*)d_in[4];
    const float* g_in = (const float*)d_in[5];
    const float* be_in = (const float*)d_in[6];
    const float* W_r1 = (const float*)d_in[7];
    const float* b_r1 = (const float*)d_in[8];
    const float* g_r1 = (const float*)d_in[9];
    const float* be_r1 = (const float*)d_in[10];
    const float* W_r2 = (const float*)d_in[11];
    const float* b_r2 = (const float*)d_in[12];
    const float* g_r2 = (const float*)d_in[13];
    const float* be_r2 = (const float*)d_in[14];
    const float* W_f  = (const float*)d_in[15];
    const float* b_f  = (const float*)d_in[16];
    const float* g_f  = (const float*)d_in[17];
    const float* be_f = (const float*)d_in[18];
    const float* W_c  = (const float*)d_in[19];
    const float* b_c  = (const float*)d_in[20];
    float* out = (float*)d_out;

    const int B = B_ROWS;

    // ---- workspace layout ----
    char* p = (char*)d_ws;
    float* pre   = (float*)p;                                            // fp32 GEMM4 out (16.8 MB)
    short* preb  = (short*)p;  p += (size_t)B * H_DIM * sizeof(float);   // bf16 GEMM1-3 out (alias)
    short* fb    = (short*)p;  p += (size_t)B * H_DIM * sizeof(short);   // bf16 running residual
    char*  act   = (char*)p;   p += (size_t)B * K1_PAD;                  // fp8 A-input (A1 aliases)
    char*  A1    = act;                                                  // B x 1088, dead after GEMM1
    char*  Wt_in = p;  p += (size_t)H_DIM * K1_PAD;
    char*  Wt_r1 = p;  p += (size_t)H_DIM * H_DIM;
    char*  Wt_r2 = p;  p += (size_t)H_DIM * H_DIM;
    char*  Wt_f  = p;  p += (size_t)P_DIM * H_DIM;

    // 1) prep: L2 norms + fp8 concat A1 (x16, K-interleaved)
    prep_a1<<<B, 256, 0, stream>>>(x1, x2, gf, A1);

    // 2) all weight transposes+cvt (x16, K-interleaved) in one launch
    transpose_cvt_all<<<dim3(K1_PAD / 64, H_DIM / 64, 4), 256, 0, stream>>>(
        W_in, Wt_in, W_r1, Wt_r1, W_r2, Wt_r2, W_f, Wt_f);

    // 3) input_proj GEMM (bf16 out) + LN -> act fp8 + residual bf16
    gemm_f8<1, K1_PAD><<<dim3(B / 128, H_DIM / 128), 256, 0, stream>>>(
        A1, Wt_in, b_in, INV_G1, nullptr, preb, H_DIM);
    ln_relu_f8<0, 1><<<B, 256, 0, stream>>>(preb, g_in, be_in, nullptr, act, fb);

    // 4) residual block 1
    gemm_f8<1, H_DIM><<<dim3(B / 128, H_DIM / 128), 256, 0, stream>>>(
        act, Wt_r1, b_r1, INV_G, nullptr, preb, H_DIM);
    ln_relu_f8<1, 1><<<B, 256, 0, stream>>>(preb, g_r1, be_r1, fb, act, fb);

    // 5) residual block 2 (no bf16 residual needed after this)
    gemm_f8<1, H_DIM><<<dim3(B / 128, H_DIM / 128), 256, 0, stream>>>(
        act, Wt_r2, b_r2, INV_G, nullptr, preb, H_DIM);
    ln_relu_f8<1, 0><<<B, 256, 0, stream>>>(preb, g_r2, be_r2, fb, act, nullptr);

    // 6) final_proj (N=256, fp32 out)
    gemm_f8<0, H_DIM><<<dim3(B / 128, P_DIM / 128), 256, 0, stream>>>(
        act, Wt_f, b_f, INV_G, pre, nullptr, P_DIM);

    // 7) fused final LN + classifier + gender mask
    ln_cls<<<B, 256, 0, stream>>>(pre, g_f, be_f, W_c, b_c, gf, out);
}

// Round 9
// 358.466 us; speedup vs baseline: 1.3029x; 1.3029x over previous
//
#include <hip/hip_runtime.h>
#include <cmath>

#define B_ROWS 16384
#define E_DIM 512
#define H_DIM 1024
#define P_DIM 256
#define K1_RAW 1026
#define K1_PAD 1088   // multiple of 64

#define NEG_BIG (-3.0e38f)
#define SCL_IN  16.0f            // fp8 pre-scale for A1 and all weights
#define INV_G1  (1.0f / 256.0f)  // GEMM1: A(x16) * W(x16)
#define INV_G   (1.0f / 16.0f)   // GEMM2-4: A(x1) * W(x16)

typedef __attribute__((ext_vector_type(4))) short short4v;
typedef __attribute__((ext_vector_type(8))) short short8v;
typedef __attribute__((ext_vector_type(4))) float f32x4;
typedef __attribute__((ext_vector_type(2))) long long2v;

__device__ __forceinline__ short f2bf(float f) {
    unsigned u = __float_as_uint(f);
    u += 0x7fffu + ((u >> 16) & 1u);   // round-to-nearest-even
    return (short)(u >> 16);
}
__device__ __forceinline__ float bf2f(short s) {
    return __uint_as_float(((unsigned)(unsigned short)s) << 16);
}
// pack 4 floats -> 4 OCP e4m3 bytes (HW cvt, RNE+sat)
__device__ __forceinline__ int pk4_fp8(float a, float b, float c, float d) {
    int v = __builtin_amdgcn_cvt_pk_fp8_f32(a, b, 0, false);
    return  __builtin_amdgcn_cvt_pk_fp8_f32(c, d, v, true);
}

// K-interleave permutation: within each 64-k block, store the 8 eight-byte
// MFMA quad-chunks as [A0 B0 A1 B1 A2 B2 A3 B3] so one b128 read at quad*16
// returns {k-step0 frag, k-step1 frag} for mfma_16x16x32_fp8_fp8.
__device__ __forceinline__ int kperm(int k) {
    return (k & ~63) | (((k >> 3) & 3) << 4) | (((k >> 5) & 1) << 3) | (k & 7);
}

// async global->LDS DMA, 16 B/lane; lds dest = wave-uniform base + lane*16
__device__ __forceinline__ void g2lds16(const void* g, void* l) {
    __builtin_amdgcn_global_load_lds(
        (const __attribute__((address_space(1))) void*)g,
        (__attribute__((address_space(3))) void*)l, 16, 0, 0);
}

// ---------------------------------------------------------------------------
// prep_a1: per-row L2 norms + emit fp8 A1[b][1088] (K-interleaved)
__global__ __launch_bounds__(256) void prep_a1(
    const float* __restrict__ x1, const float* __restrict__ x2,
    const float* __restrict__ gf, char* __restrict__ A1)
{
    const int b = blockIdx.x;
    const int t = threadIdx.x;
    __shared__ float red[4];

    const float* src = (t < 128) ? x1 : x2;
    const int idx = (t & 127) << 2;
    float4 v = *(const float4*)&src[(size_t)b * E_DIM + idx];
    float ss = v.x*v.x + v.y*v.y + v.z*v.z + v.w*v.w;
    #pragma unroll
    for (int off = 32; off > 0; off >>= 1) ss += __shfl_xor(ss, off, 64);
    if ((t & 63) == 0) red[t >> 6] = ss;
    __syncthreads();
    const float inv1 = SCL_IN / fmaxf(sqrtf(red[0] + red[1]), 1e-12f);
    const float inv2 = SCL_IN / fmaxf(sqrtf(red[2] + red[3]), 1e-12f);

    const size_t rb = (size_t)b * K1_PAD;
    {
        const int k = t << 2;   // 0..1020
        const float* s = (k < E_DIM) ? &x1[(size_t)b * E_DIM + k]
                                     : &x2[(size_t)b * E_DIM + k - E_DIM];
        const float iv = (k < E_DIM) ? inv1 : inv2;
        float4 u = *(const float4*)s;
        *(int*)&A1[rb + kperm(k)] = pk4_fp8(u.x * iv, u.y * iv, u.z * iv, u.w * iv);
    }
    if (t < 16) {
        const int k = 1024 + (t << 2);   // covers full pad block
        float vals[4];
        #pragma unroll
        for (int i = 0; i < 4; ++i) {
            int kk = k + i;
            vals[i] = (kk == 1024) ? gf[(size_t)b * 2 + 0] * SCL_IN
                    : (kk == 1025) ? gf[(size_t)b * 2 + 1] * SCL_IN : 0.f;
        }
        *(int*)&A1[rb + kperm(k)] = pk4_fp8(vals[0], vals[1], vals[2], vals[3]);
    }
}

// ---------------------------------------------------------------------------
// transpose_cvt_all: W fp32 [K][N] -> Wt fp8 [N][Kpad] (K-interleaved, x16).
__global__ __launch_bounds__(256) void transpose_cvt_all(
    const float* __restrict__ W0, char* __restrict__ Wt0,
    const float* __restrict__ W1, char* __restrict__ Wt1,
    const float* __restrict__ W2, char* __restrict__ Wt2,
    const float* __restrict__ W3, char* __restrict__ Wt3)
{
    const int z = blockIdx.z;
    const float* W; char* Wt; int K, N, Kpad;
    if (z == 0)      { W = W0; Wt = Wt0; K = K1_RAW; N = H_DIM; Kpad = K1_PAD; }
    else if (z == 1) { W = W1; Wt = Wt1; K = H_DIM;  N = H_DIM; Kpad = H_DIM; }
    else if (z == 2) { W = W2; Wt = Wt2; K = H_DIM;  N = H_DIM; Kpad = H_DIM; }
    else             { W = W3; Wt = Wt3; K = H_DIM;  N = P_DIM; Kpad = H_DIM; }

    const int k0 = blockIdx.x * 64, n0 = blockIdx.y * 64;
    if (k0 >= Kpad || n0 >= N) return;

    __shared__ float T[64][68];
    const int t = threadIdx.x;
    const int r = t >> 4;          // 0..15
    const int c = (t & 15) << 2;   // 0..60
    #pragma unroll
    for (int rr = 0; rr < 4; ++rr) {
        int k = k0 + r + rr * 16;
        float4 v = (k < K) ? *(const float4*)&W[(size_t)k * N + n0 + c]
                           : make_float4(0.f, 0.f, 0.f, 0.f);
        v.x *= SCL_IN; v.y *= SCL_IN; v.z *= SCL_IN; v.w *= SCL_IN;
        *(float4*)&T[r + rr * 16][c] = v;
    }
    __syncthreads();
    const int n = n0 + (t >> 2);
    const int cn = t >> 2;
    const int ks = (t & 3) << 4;   // 0,16,32,48
    #pragma unroll
    for (int g = 0; g < 2; ++g) {
        int kk = ks + g * 8;
        int k = k0 + kk;
        if (k + 7 < Kpad) {
            int lo = pk4_fp8(T[kk+0][cn], T[kk+1][cn], T[kk+2][cn], T[kk+3][cn]);
            int hi = pk4_fp8(T[kk+4][cn], T[kk+5][cn], T[kk+6][cn], T[kk+7][cn]);
            int2 o = { lo, hi };
            int np = k0 + (((kk >> 3) & 3) << 4) + (((kk >> 5) & 1) << 3);
            *(int2*)&Wt[(size_t)n * Kpad + np] = o;
        }
    }
}

// ---------------------------------------------------------------------------
// gemm_f8: C[M,N](bf16) = A[M,KA](fp8,K-ilv) @ Bt[N,KA]^T(fp8,K-ilv)*cscale+bias
// Tile 128 x (64*NWN), 2*NWN waves (NWN=4: 512 thr, grid 512 = exactly 2
// blocks/CU -> 16 waves/CU; NWN=2: 256 thr for N=256). Double-buffered
// global_load_lds K-loop (BK=64, conflict-free b128 frag reads), LDS reused
// for a coalesced staged epilogue (r8-proven, WRITE_SIZE 55->17 MB).
template <int NWN, int KA>
__global__ __launch_bounds__(NWN * 128) void gemm_f8(
    const char* __restrict__ A, const char* __restrict__ Bt,
    const float* __restrict__ bias, float cscale,
    short* __restrict__ Cb, int N)
{
    constexpr int WAVES = 2 * NWN;
    constexpr int TN    = 64 * NWN;
    constexpr int NK    = KA >> 6;
    constexpr int A_PW  = 8 / WAVES;          // A 16-row chunks per wave
    constexpr int B_PW  = (TN / 16) / WAVES;  // = 2
    constexpr int KBUF  = (128 + TN) * 64;    // bytes per double-buffer slot
    constexpr int STAGE = 128 * 132 * 2;      // bf16 epilogue chunk
    constexpr int LDSZ  = (2 * KBUF > STAGE) ? 2 * KBUF : STAGE;

    __shared__ __align__(16) char smem[LDSZ];

    const int t = threadIdx.x;
    const int w = t >> 6, lane = t & 63;
    const int wm = w & 1, wn = w >> 1;
    const int m16 = lane & 15, quad = lane >> 4;
    const int row0 = blockIdx.x * 128, col0 = blockIdx.y * TN;

    const int wu = __builtin_amdgcn_readfirstlane(w);
    // chunk c = 16 rows; lane l covers row c*16+(l>>2), bytes (l&3)*16
    const char* Ag[A_PW];
    const char* Bg[B_PW];
    #pragma unroll
    for (int i = 0; i < A_PW; ++i) {
        int c = wu * A_PW + i;
        Ag[i] = A + (size_t)(row0 + c * 16 + (lane >> 2)) * KA + ((lane & 3) << 4);
    }
    #pragma unroll
    for (int i = 0; i < B_PW; ++i) {
        int c = wu * B_PW + i;
        Bg[i] = Bt + (size_t)(col0 + c * 16 + (lane >> 2)) * KA + ((lane & 3) << 4);
    }

    auto issue = [&](int kt, int bi) {
        char* As = smem + bi * KBUF;
        char* Bs = smem + bi * KBUF + 128 * 64;
        const size_t ko = (size_t)kt << 6;
        #pragma unroll
        for (int i = 0; i < A_PW; ++i)
            g2lds16(Ag[i] + ko, As + (wu * A_PW + i) * 1024);
        #pragma unroll
        for (int i = 0; i < B_PW; ++i)
            g2lds16(Bg[i] + ko, Bs + (wu * B_PW + i) * 1024);
    };

    f32x4 acc[4][4];
    #pragma unroll
    for (int i = 0; i < 4; ++i)
        #pragma unroll
        for (int j = 0; j < 4; ++j)
            acc[i][j] = (f32x4){0.f, 0.f, 0.f, 0.f};

    issue(0, 0);

    for (int kt = 0; kt < NK; ++kt) {
        // all prior DMAs done (tile kt resident) + all waves done reading
        // the buffer tile kt+1 will overwrite
        asm volatile("s_waitcnt vmcnt(0)\n\ts_barrier" ::: "memory");
        if (kt + 1 < NK) issue(kt + 1, (kt + 1) & 1);

        const char* As = smem + (kt & 1) * KBUF;
        const char* Bs = smem + (kt & 1) * KBUF + 128 * 64;
        long2v a2[4], b2[4];
        #pragma unroll
        for (int i = 0; i < 4; ++i)
            a2[i] = *(const long2v*)&As[(wm * 64 + i * 16 + m16) * 64 + quad * 16];
        #pragma unroll
        for (int j = 0; j < 4; ++j)
            b2[j] = *(const long2v*)&Bs[(wn * 64 + j * 16 + m16) * 64 + quad * 16];
        #pragma unroll
        for (int i = 0; i < 4; ++i)
            #pragma unroll
            for (int j = 0; j < 4; ++j) {
                acc[i][j] = __builtin_amdgcn_mfma_f32_16x16x32_fp8_fp8(
                    a2[i][0], b2[j][0], acc[i][j], 0, 0, 0);
                acc[i][j] = __builtin_amdgcn_mfma_f32_16x16x32_fp8_fp8(
                    a2[i][1], b2[j][1], acc[i][j], 0, 0, 0);
            }
    }

    // ---- staged epilogue, 128-col chunks, reusing K-loop LDS ----
    float bj[4];
    #pragma unroll
    for (int j = 0; j < 4; ++j)
        bj[j] = bias[col0 + wn * 64 + j * 16 + m16];

    short* Cs = (short*)smem;   // [128][132]
    #pragma unroll
    for (int ch = 0; ch < NWN / 2; ++ch) {
        __syncthreads();   // K-loop reads / previous chunk's stores done
        if ((wn >> 1) == ch) {
            const int colIn = (wn & 1) * 64;
            #pragma unroll
            for (int j = 0; j < 4; ++j) {
                const int cc = colIn + j * 16 + m16;
                #pragma unroll
                for (int i = 0; i < 4; ++i) {
                    const int rbase = wm * 64 + i * 16 + quad * 4;
                    #pragma unroll
                    for (int r = 0; r < 4; ++r)
                        Cs[(rbase + r) * 132 + cc] = f2bf(acc[i][j][r] * cscale + bj[j]);
                }
            }
        }
        __syncthreads();
        // 128 rows x 128 cols bf16 = 2048 short8 stores over NWN*128 threads
        #pragma unroll
        for (int i = 0; i < 2048 / (NWN * 128); ++i) {
            const int idx = i * NWN * 128 + t;
            const int r = idx >> 4, c8 = idx & 15;
            short8v v = *(const short8v*)&Cs[r * 132 + c8 * 8];
            *(short8v*)&Cb[(size_t)(row0 + r) * N + col0 + ch * 128 + c8 * 8] = v;
        }
    }
}

// ---------------------------------------------------------------------------
__device__ __forceinline__ void block_reduce2(float& s, float& ss)
{
    __shared__ float red[2][4];
    #pragma unroll
    for (int off = 32; off > 0; off >>= 1) {
        s  += __shfl_xor(s,  off, 64);
        ss += __shfl_xor(ss, off, 64);
    }
    int lane = threadIdx.x & 63, w = threadIdx.x >> 6;
    if (lane == 0) { red[0][w] = s; red[1][w] = ss; }
    __syncthreads();
    if (threadIdx.x == 0) {
        red[0][0] = red[0][0] + red[0][1] + red[0][2] + red[0][3];
        red[1][0] = red[1][0] + red[1][1] + red[1][2] + red[1][3];
    }
    __syncthreads();
    s = red[0][0]; ss = red[1][0];
}

// LN+ReLU over bf16 GEMM out (+bf16 residual). Writes fp8 act (K-interleaved)
// and optionally bf16 running residual.
template <int HAS_RES, int WRITE_BF>
__global__ __launch_bounds__(256) void ln_relu_f8(
    const short* __restrict__ X, const float* __restrict__ gamma,
    const float* __restrict__ beta, const short* __restrict__ res,
    char* __restrict__ act, short* __restrict__ resout)
{
    const int row = blockIdx.x;
    const size_t base = (size_t)row * H_DIM;
    const int idx = threadIdx.x << 2;
    short4v xb = *(const short4v*)&X[base + idx];
    float4 x = { bf2f(xb[0]), bf2f(xb[1]), bf2f(xb[2]), bf2f(xb[3]) };
    float s  = x.x + x.y + x.z + x.w;
    float ss = x.x*x.x + x.y*x.y + x.z*x.z + x.w*x.w;
    block_reduce2(s, ss);
    float m = s * (1.f / H_DIM);
    float var = fmaxf(ss * (1.f / H_DIM) - m * m, 0.f);
    float r = 1.f / sqrtf(var + 1e-5f);
    float4 g  = *(const float4*)&gamma[idx];
    float4 be = *(const float4*)&beta[idx];
    float4 y;
    y.x = fmaxf((x.x - m) * r * g.x + be.x, 0.f);
    y.y = fmaxf((x.y - m) * r * g.y + be.y, 0.f);
    y.z = fmaxf((x.z - m) * r * g.z + be.z, 0.f);
    y.w = fmaxf((x.w - m) * r * g.w + be.w, 0.f);
    if (HAS_RES) {
        short4v rr = *(const short4v*)&res[base + idx];
        y.x += bf2f(rr[0]); y.y += bf2f(rr[1]); y.z += bf2f(rr[2]); y.w += bf2f(rr[3]);
    }
    *(int*)&act[base + kperm(idx)] = pk4_fp8(y.x, y.y, y.z, y.w);
    if (WRITE_BF) {
        short4v o = { f2bf(y.x), f2bf(y.y), f2bf(y.z), f2bf(y.w) };
        *(short4v*)&resout[base + idx] = o;
    }
}

// ---------------------------------------------------------------------------
// fused final LN (H=256, bf16 in) + classifier + gender mask
__global__ __launch_bounds__(256) void ln_cls(
    const short* __restrict__ X, const float* __restrict__ gamma,
    const float* __restrict__ beta, const float* __restrict__ Wc,
    const float* __restrict__ bc, const float* __restrict__ gf,
    float* __restrict__ out)
{
    const int row = blockIdx.x;
    const size_t base = (size_t)row * P_DIM;
    const int t = threadIdx.x;
    float x = bf2f(X[base + t]);
    float s = x, ss = x * x;
    block_reduce2(s, ss);
    float m = s * (1.f / P_DIM);
    float var = fmaxf(ss * (1.f / P_DIM) - m * m, 0.f);
    float r = 1.f / sqrtf(var + 1e-5f);
    float y = fmaxf((x - m) * r * gamma[t] + beta[t], 0.f);

    __shared__ float part[4][8];
    const int lane = t & 63, w = t >> 6;
    #pragma unroll
    for (int c = 0; c < 7; ++c) {
        float v = y * Wc[t * 7 + c];
        #pragma unroll
        for (int off = 32; off > 0; off >>= 1) v += __shfl_xor(v, off, 64);
        if (lane == 0) part[w][c] = v;
    }
    __syncthreads();
    if (t < 7) {
        float v = part[0][t] + part[1][t] + part[2][t] + part[3][t] + bc[t];
        int g1 = (gf[(size_t)row * 2 + 0] != 0.f);
        int g2 = (gf[(size_t)row * 2 + 1] != 0.f);
        unsigned bits = (g1 == g2) ? (g1 ? 0x24u : 0x12u) : 0x49u;
        out[(size_t)row * 7 + t] = ((bits >> t) & 1u) ? v : NEG_BIG;
    }
}

// ---------------------------------------------------------------------------
extern "C" void kernel_launch(void* const* d_in, const int* in_sizes, int n_in,
                              void* d_out, int out_size, void* d_ws, size_t ws_size,
                              hipStream_t stream)
{
    const float* x1   = (const float*)d_in[0];
    const float* x2   = (const float*)d_in[1];
    const float* gf   = (const float*)d_in[2];
    const float* W_in = (const float*)d_in[3];
    const float* b_in = (const float*)d_in[4];
    const float* g_in = (const float*)d_in[5];
    const float* be_in = (const float*)d_in[6];
    const float* W_r1 = (const float*)d_in[7];
    const float* b_r1 = (const float*)d_in[8];
    const float* g_r1 = (const float*)d_in[9];
    const float* be_r1 = (const float*)d_in[10];
    const float* W_r2 = (const float*)d_in[11];
    const float* b_r2 = (const float*)d_in[12];
    const float* g_r2 = (const float*)d_in[13];
    const float* be_r2 = (const float*)d_in[14];
    const float* W_f  = (const float*)d_in[15];
    const float* b_f  = (const float*)d_in[16];
    const float* g_f  = (const float*)d_in[17];
    const float* be_f = (const float*)d_in[18];
    const float* W_c  = (const float*)d_in[19];
    const float* b_c  = (const float*)d_in[20];
    float* out = (float*)d_out;

    const int B = B_ROWS;

    // ---- workspace layout ----
    char* p = (char*)d_ws;
    short* preb  = (short*)p;  p += (size_t)B * H_DIM * sizeof(float);   // bf16 GEMM out
    short* fb    = (short*)p;  p += (size_t)B * H_DIM * sizeof(short);   // bf16 running residual
    char*  act   = (char*)p;   p += (size_t)B * K1_PAD;                  // fp8 A-input
    char*  A1    = act;                                                  // aliases (dead after GEMM1)
    char*  Wt_in = p;  p += (size_t)H_DIM * K1_PAD;
    char*  Wt_r1 = p;  p += (size_t)H_DIM * H_DIM;
    char*  Wt_r2 = p;  p += (size_t)H_DIM * H_DIM;
    char*  Wt_f  = p;  p += (size_t)P_DIM * H_DIM;

    // 1) prep: L2 norms + fp8 concat A1 (x16, K-interleaved)
    prep_a1<<<B, 256, 0, stream>>>(x1, x2, gf, A1);

    // 2) all weight transposes+cvt (x16, K-interleaved) in one launch
    transpose_cvt_all<<<dim3(K1_PAD / 64, H_DIM / 64, 4), 256, 0, stream>>>(
        W_in, Wt_in, W_r1, Wt_r1, W_r2, Wt_r2, W_f, Wt_f);

    // 3) input_proj GEMM + LN -> act fp8 + residual bf16
    gemm_f8<4, K1_PAD><<<dim3(B / 128, H_DIM / 256), 512, 0, stream>>>(
        A1, Wt_in, b_in, INV_G1, preb, H_DIM);
    ln_relu_f8<0, 1><<<B, 256, 0, stream>>>(preb, g_in, be_in, nullptr, act, fb);

    // 4) residual block 1
    gemm_f8<4, H_DIM><<<dim3(B / 128, H_DIM / 256), 512, 0, stream>>>(
        act, Wt_r1, b_r1, INV_G, preb, H_DIM);
    ln_relu_f8<1, 1><<<B, 256, 0, stream>>>(preb, g_r1, be_r1, fb, act, fb);

    // 5) residual block 2 (no bf16 residual needed after this)
    gemm_f8<4, H_DIM><<<dim3(B / 128, H_DIM / 256), 512, 0, stream>>>(
        act, Wt_r2, b_r2, INV_G, preb, H_DIM);
    ln_relu_f8<1, 0><<<B, 256, 0, stream>>>(preb, g_r2, be_r2, fb, act, nullptr);

    // 6) final_proj (N=256, bf16 out, 4-wave tile -> grid 256 = 1/CU)
    gemm_f8<2, H_DIM><<<dim3(B / 128, P_DIM / 128), 256, 0, stream>>>(
        act, Wt_f, b_f, INV_G, preb, P_DIM);

    // 7) fused final LN + classifier + gender mask
    ln_cls<<<B, 256, 0, stream>>>(preb, g_f, be_f, W_c, b_c, gf, out);
}

// Round 10
// 325.346 us; speedup vs baseline: 1.4355x; 1.1018x over previous
//
#include <hip/hip_runtime.h>
#include <cmath>

#define B_ROWS 16384
#define E_DIM 512
#define H_DIM 1024
#define P_DIM 256
#define K1_RAW 1026
#define K1_PAD 1088   // multiple of 64

#define NEG_BIG (-3.0e38f)
#define SCL_IN  16.0f            // fp8 pre-scale for A1 and all weights
#define INV_G1  (1.0f / 256.0f)  // GEMM1: A(x16) * W(x16)
#define INV_G   (1.0f / 16.0f)   // GEMM2-4: A(x1) * W(x16)

typedef __attribute__((ext_vector_type(4))) short short4v;
typedef __attribute__((ext_vector_type(8))) short short8v;
typedef __attribute__((ext_vector_type(4))) float f32x4;
typedef __attribute__((ext_vector_type(2))) long long2v;

__device__ __forceinline__ short f2bf(float f) {
    unsigned u = __float_as_uint(f);
    u += 0x7fffu + ((u >> 16) & 1u);   // round-to-nearest-even
    return (short)(u >> 16);
}
__device__ __forceinline__ float bf2f(short s) {
    return __uint_as_float(((unsigned)(unsigned short)s) << 16);
}
// pack 4 floats -> 4 OCP e4m3 bytes (HW cvt, RNE+sat)
__device__ __forceinline__ int pk4_fp8(float a, float b, float c, float d) {
    int v = __builtin_amdgcn_cvt_pk_fp8_f32(a, b, 0, false);
    return  __builtin_amdgcn_cvt_pk_fp8_f32(c, d, v, true);
}

// K-interleave permutation: within each 64-k block, store the 8 eight-byte
// MFMA quad-chunks as [A0 B0 A1 B1 A2 B2 A3 B3] so one b128 read at quad*16
// returns {k-step0 frag, k-step1 frag} for mfma_16x16x32_fp8_fp8.
__device__ __forceinline__ int kperm(int k) {
    return (k & ~63) | (((k >> 3) & 3) << 4) | (((k >> 5) & 1) << 3) | (k & 7);
}

// async global->LDS DMA, 16 B/lane; lds dest = wave-uniform base + lane*16
__device__ __forceinline__ void g2lds16(const void* g, void* l) {
    __builtin_amdgcn_global_load_lds(
        (const __attribute__((address_space(1))) void*)g,
        (__attribute__((address_space(3))) void*)l, 16, 0, 0);
}

// ---------------------------------------------------------------------------
// prep_a1: per-row L2 norms + emit fp8 A1[b][1088] (K-interleaved)
__global__ __launch_bounds__(256) void prep_a1(
    const float* __restrict__ x1, const float* __restrict__ x2,
    const float* __restrict__ gf, char* __restrict__ A1)
{
    const int b = blockIdx.x;
    const int t = threadIdx.x;
    __shared__ float red[4];

    const float* src = (t < 128) ? x1 : x2;
    const int idx = (t & 127) << 2;
    float4 v = *(const float4*)&src[(size_t)b * E_DIM + idx];
    float ss = v.x*v.x + v.y*v.y + v.z*v.z + v.w*v.w;
    #pragma unroll
    for (int off = 32; off > 0; off >>= 1) ss += __shfl_xor(ss, off, 64);
    if ((t & 63) == 0) red[t >> 6] = ss;
    __syncthreads();
    const float inv1 = SCL_IN / fmaxf(sqrtf(red[0] + red[1]), 1e-12f);
    const float inv2 = SCL_IN / fmaxf(sqrtf(red[2] + red[3]), 1e-12f);

    const size_t rb = (size_t)b * K1_PAD;
    {
        const int k = t << 2;   // 0..1020
        const float* s = (k < E_DIM) ? &x1[(size_t)b * E_DIM + k]
                                     : &x2[(size_t)b * E_DIM + k - E_DIM];
        const float iv = (k < E_DIM) ? inv1 : inv2;
        float4 u = *(const float4*)s;
        *(int*)&A1[rb + kperm(k)] = pk4_fp8(u.x * iv, u.y * iv, u.z * iv, u.w * iv);
    }
    if (t < 16) {
        const int k = 1024 + (t << 2);   // covers full pad block
        float vals[4];
        #pragma unroll
        for (int i = 0; i < 4; ++i) {
            int kk = k + i;
            vals[i] = (kk == 1024) ? gf[(size_t)b * 2 + 0] * SCL_IN
                    : (kk == 1025) ? gf[(size_t)b * 2 + 1] * SCL_IN : 0.f;
        }
        *(int*)&A1[rb + kperm(k)] = pk4_fp8(vals[0], vals[1], vals[2], vals[3]);
    }
}

// ---------------------------------------------------------------------------
// transpose_cvt_all: W fp32 [K][N] -> Wt fp8 [N][Kpad] (K-interleaved, x16).
__global__ __launch_bounds__(256) void transpose_cvt_all(
    const float* __restrict__ W0, char* __restrict__ Wt0,
    const float* __restrict__ W1, char* __restrict__ Wt1,
    const float* __restrict__ W2, char* __restrict__ Wt2,
    const float* __restrict__ W3, char* __restrict__ Wt3)
{
    const int z = blockIdx.z;
    const float* W; char* Wt; int K, N, Kpad;
    if (z == 0)      { W = W0; Wt = Wt0; K = K1_RAW; N = H_DIM; Kpad = K1_PAD; }
    else if (z == 1) { W = W1; Wt = Wt1; K = H_DIM;  N = H_DIM; Kpad = H_DIM; }
    else if (z == 2) { W = W2; Wt = Wt2; K = H_DIM;  N = H_DIM; Kpad = H_DIM; }
    else             { W = W3; Wt = Wt3; K = H_DIM;  N = P_DIM; Kpad = H_DIM; }

    const int k0 = blockIdx.x * 64, n0 = blockIdx.y * 64;
    if (k0 >= Kpad || n0 >= N) return;

    __shared__ float T[64][68];
    const int t = threadIdx.x;
    const int r = t >> 4;          // 0..15
    const int c = (t & 15) << 2;   // 0..60
    #pragma unroll
    for (int rr = 0; rr < 4; ++rr) {
        int k = k0 + r + rr * 16;
        float4 v = (k < K) ? *(const float4*)&W[(size_t)k * N + n0 + c]
                           : make_float4(0.f, 0.f, 0.f, 0.f);
        v.x *= SCL_IN; v.y *= SCL_IN; v.z *= SCL_IN; v.w *= SCL_IN;
        *(float4*)&T[r + rr * 16][c] = v;
    }
    __syncthreads();
    const int n = n0 + (t >> 2);
    const int cn = t >> 2;
    const int ks = (t & 3) << 4;   // 0,16,32,48
    #pragma unroll
    for (int g = 0; g < 2; ++g) {
        int kk = ks + g * 8;
        int k = k0 + kk;
        if (k + 7 < Kpad) {
            int lo = pk4_fp8(T[kk+0][cn], T[kk+1][cn], T[kk+2][cn], T[kk+3][cn]);
            int hi = pk4_fp8(T[kk+4][cn], T[kk+5][cn], T[kk+6][cn], T[kk+7][cn]);
            int2 o = { lo, hi };
            int np = k0 + (((kk >> 3) & 3) << 4) + (((kk >> 5) & 1) << 3);
            *(int2*)&Wt[(size_t)n * Kpad + np] = o;
        }
    }
}

// ---------------------------------------------------------------------------
// gemm_f8: C[M,N](bf16) = A[M,KA](fp8,K-ilv) @ Bt[N,KA]^T(fp8,K-ilv)*cscale+bias
// Tile 128 x (64*NWN), 2*NWN waves (NWN=4: 512 thr, grid 512 = exactly 2
// blocks/CU -> 16 waves/CU). Double-buffered global_load_lds K-loop (BK=64,
// conflict-free b128 frag reads), LDS reused for coalesced staged epilogue.
template <int NWN, int KA>
__global__ __launch_bounds__(NWN * 128) void gemm_f8(
    const char* __restrict__ A, const char* __restrict__ Bt,
    const float* __restrict__ bias, float cscale,
    short* __restrict__ Cb, int N)
{
    constexpr int WAVES = 2 * NWN;
    constexpr int TN    = 64 * NWN;
    constexpr int NK    = KA >> 6;
    constexpr int A_PW  = 8 / WAVES;          // A 16-row chunks per wave
    constexpr int B_PW  = (TN / 16) / WAVES;  // = 2
    constexpr int KBUF  = (128 + TN) * 64;    // bytes per double-buffer slot
    constexpr int STAGE = 128 * 132 * 2;      // bf16 epilogue chunk
    constexpr int LDSZ  = (2 * KBUF > STAGE) ? 2 * KBUF : STAGE;

    __shared__ __align__(16) char smem[LDSZ];

    const int t = threadIdx.x;
    const int w = t >> 6, lane = t & 63;
    const int wm = w & 1, wn = w >> 1;
    const int m16 = lane & 15, quad = lane >> 4;
    const int row0 = blockIdx.x * 128, col0 = blockIdx.y * TN;

    const int wu = __builtin_amdgcn_readfirstlane(w);
    const char* Ag[A_PW];
    const char* Bg[B_PW];
    #pragma unroll
    for (int i = 0; i < A_PW; ++i) {
        int c = wu * A_PW + i;
        Ag[i] = A + (size_t)(row0 + c * 16 + (lane >> 2)) * KA + ((lane & 3) << 4);
    }
    #pragma unroll
    for (int i = 0; i < B_PW; ++i) {
        int c = wu * B_PW + i;
        Bg[i] = Bt + (size_t)(col0 + c * 16 + (lane >> 2)) * KA + ((lane & 3) << 4);
    }

    auto issue = [&](int kt, int bi) {
        char* As = smem + bi * KBUF;
        char* Bs = smem + bi * KBUF + 128 * 64;
        const size_t ko = (size_t)kt << 6;
        #pragma unroll
        for (int i = 0; i < A_PW; ++i)
            g2lds16(Ag[i] + ko, As + (wu * A_PW + i) * 1024);
        #pragma unroll
        for (int i = 0; i < B_PW; ++i)
            g2lds16(Bg[i] + ko, Bs + (wu * B_PW + i) * 1024);
    };

    f32x4 acc[4][4];
    #pragma unroll
    for (int i = 0; i < 4; ++i)
        #pragma unroll
        for (int j = 0; j < 4; ++j)
            acc[i][j] = (f32x4){0.f, 0.f, 0.f, 0.f};

    issue(0, 0);

    for (int kt = 0; kt < NK; ++kt) {
        asm volatile("s_waitcnt vmcnt(0)\n\ts_barrier" ::: "memory");
        if (kt + 1 < NK) issue(kt + 1, (kt + 1) & 1);

        const char* As = smem + (kt & 1) * KBUF;
        const char* Bs = smem + (kt & 1) * KBUF + 128 * 64;
        long2v a2[4], b2[4];
        #pragma unroll
        for (int i = 0; i < 4; ++i)
            a2[i] = *(const long2v*)&As[(wm * 64 + i * 16 + m16) * 64 + quad * 16];
        #pragma unroll
        for (int j = 0; j < 4; ++j)
            b2[j] = *(const long2v*)&Bs[(wn * 64 + j * 16 + m16) * 64 + quad * 16];
        #pragma unroll
        for (int i = 0; i < 4; ++i)
            #pragma unroll
            for (int j = 0; j < 4; ++j) {
                acc[i][j] = __builtin_amdgcn_mfma_f32_16x16x32_fp8_fp8(
                    a2[i][0], b2[j][0], acc[i][j], 0, 0, 0);
                acc[i][j] = __builtin_amdgcn_mfma_f32_16x16x32_fp8_fp8(
                    a2[i][1], b2[j][1], acc[i][j], 0, 0, 0);
            }
    }

    // ---- staged epilogue, 128-col chunks, reusing K-loop LDS ----
    float bj[4];
    #pragma unroll
    for (int j = 0; j < 4; ++j)
        bj[j] = bias[col0 + wn * 64 + j * 16 + m16];

    short* Cs = (short*)smem;   // [128][132]
    #pragma unroll
    for (int ch = 0; ch < NWN / 2; ++ch) {
        __syncthreads();
        if ((wn >> 1) == ch) {
            const int colIn = (wn & 1) * 64;
            #pragma unroll
            for (int j = 0; j < 4; ++j) {
                const int cc = colIn + j * 16 + m16;
                #pragma unroll
                for (int i = 0; i < 4; ++i) {
                    const int rbase = wm * 64 + i * 16 + quad * 4;
                    #pragma unroll
                    for (int r = 0; r < 4; ++r)
                        Cs[(rbase + r) * 132 + cc] = f2bf(acc[i][j][r] * cscale + bj[j]);
                }
            }
        }
        __syncthreads();
        #pragma unroll
        for (int i = 0; i < 2048 / (NWN * 128); ++i) {
            const int idx = i * NWN * 128 + t;
            const int r = idx >> 4, c8 = idx & 15;
            short8v v = *(const short8v*)&Cs[r * 132 + c8 * 8];
            *(short8v*)&Cb[(size_t)(row0 + r) * N + col0 + ch * 128 + c8 * 8] = v;
        }
    }
}

// ---------------------------------------------------------------------------
// LN+ReLU, ONE WAVE PER ROW (4 rows/block, no barriers). bf16 in, fp8 out
// (K-interleaved) + optional bf16 running residual.
template <int HAS_RES, int WRITE_BF>
__global__ __launch_bounds__(256) void ln_relu_f8(
    const short* __restrict__ X, const float* __restrict__ gamma,
    const float* __restrict__ beta, const short* __restrict__ res,
    char* __restrict__ act, short* __restrict__ resout)
{
    const int row  = blockIdx.x * 4 + (threadIdx.x >> 6);
    const int lane = threadIdx.x & 63;
    const size_t base = (size_t)row * H_DIM;

    float y[4][4];
    float s = 0.f, ss = 0.f;
    #pragma unroll
    for (int j = 0; j < 4; ++j) {
        const int idx = j * 256 + lane * 4;
        short4v xb = *(const short4v*)&X[base + idx];
        #pragma unroll
        for (int e = 0; e < 4; ++e) {
            float xv = bf2f(xb[e]);
            y[j][e] = xv;
            s += xv; ss += xv * xv;
        }
    }
    #pragma unroll
    for (int off = 32; off > 0; off >>= 1) {
        s  += __shfl_xor(s,  off, 64);
        ss += __shfl_xor(ss, off, 64);
    }
    const float m = s * (1.f / H_DIM);
    const float var = fmaxf(ss * (1.f / H_DIM) - m * m, 0.f);
    const float r = 1.f / sqrtf(var + 1e-5f);

    #pragma unroll
    for (int j = 0; j < 4; ++j) {
        const int idx = j * 256 + lane * 4;
        float4 g  = *(const float4*)&gamma[idx];
        float4 be = *(const float4*)&beta[idx];
        float gv[4] = { g.x, g.y, g.z, g.w };
        float bv[4] = { be.x, be.y, be.z, be.w };
        #pragma unroll
        for (int e = 0; e < 4; ++e)
            y[j][e] = fmaxf((y[j][e] - m) * r * gv[e] + bv[e], 0.f);
        if (HAS_RES) {
            short4v rr = *(const short4v*)&res[base + idx];
            #pragma unroll
            for (int e = 0; e < 4; ++e) y[j][e] += bf2f(rr[e]);
        }
        *(int*)&act[base + kperm(idx)] = pk4_fp8(y[j][0], y[j][1], y[j][2], y[j][3]);
        if (WRITE_BF) {
            short4v o = { f2bf(y[j][0]), f2bf(y[j][1]), f2bf(y[j][2]), f2bf(y[j][3]) };
            *(short4v*)&resout[base + idx] = o;
        }
    }
}

// ---------------------------------------------------------------------------
// fused final LN (H=256, bf16 in) + classifier + gender mask.
// ONE WAVE PER ROW (4 rows/block, no barriers, no LDS).
__global__ __launch_bounds__(256) void ln_cls(
    const short* __restrict__ X, const float* __restrict__ gamma,
    const float* __restrict__ beta, const float* __restrict__ Wc,
    const float* __restrict__ bc, const float* __restrict__ gf,
    float* __restrict__ out)
{
    const int row  = blockIdx.x * 4 + (threadIdx.x >> 6);
    const int lane = threadIdx.x & 63;
    const size_t base = (size_t)row * P_DIM;
    const int k0 = lane * 4;

    short4v xb = *(const short4v*)&X[base + k0];
    float x[4];
    float s = 0.f, ss = 0.f;
    #pragma unroll
    for (int e = 0; e < 4; ++e) {
        x[e] = bf2f(xb[e]);
        s += x[e]; ss += x[e] * x[e];
    }
    #pragma unroll
    for (int off = 32; off > 0; off >>= 1) {
        s  += __shfl_xor(s,  off, 64);
        ss += __shfl_xor(ss, off, 64);
    }
    const float m = s * (1.f / P_DIM);
    const float var = fmaxf(ss * (1.f / P_DIM) - m * m, 0.f);
    const float r = 1.f / sqrtf(var + 1e-5f);

    float4 g  = *(const float4*)&gamma[k0];
    float4 be = *(const float4*)&beta[k0];
    float gv[4] = { g.x, g.y, g.z, g.w };
    float bv[4] = { be.x, be.y, be.z, be.w };
    float yv[4];
    #pragma unroll
    for (int e = 0; e < 4; ++e)
        yv[e] = fmaxf((x[e] - m) * r * gv[e] + bv[e], 0.f);

    float p[7] = {0.f, 0.f, 0.f, 0.f, 0.f, 0.f, 0.f};
    #pragma unroll
    for (int e = 0; e < 4; ++e) {
        const float* wr = &Wc[(k0 + e) * 7];
        #pragma unroll
        for (int c = 0; c < 7; ++c) p[c] += yv[e] * wr[c];
    }
    #pragma unroll
    for (int off = 32; off > 0; off >>= 1)
        #pragma unroll
        for (int c = 0; c < 7; ++c) p[c] += __shfl_xor(p[c], off, 64);

    if (lane == 0) {
        int g1 = (gf[(size_t)row * 2 + 0] != 0.f);
        int g2 = (gf[(size_t)row * 2 + 1] != 0.f);
        unsigned bits = (g1 == g2) ? (g1 ? 0x24u : 0x12u) : 0x49u;
        #pragma unroll
        for (int c = 0; c < 7; ++c)
            out[(size_t)row * 7 + c] = ((bits >> c) & 1u) ? p[c] + bc[c] : NEG_BIG;
    }
}

// ---------------------------------------------------------------------------
extern "C" void kernel_launch(void* const* d_in, const int* in_sizes, int n_in,
                              void* d_out, int out_size, void* d_ws, size_t ws_size,
                              hipStream_t stream)
{
    const float* x1   = (const float*)d_in[0];
    const float* x2   = (const float*)d_in[1];
    const float* gf   = (const float*)d_in[2];
    const float* W_in = (const float*)d_in[3];
    const float* b_in = (const float*)d_in[4];
    const float* g_in = (const float*)d_in[5];
    const float* be_in = (const float*)d_in[6];
    const float* W_r1 = (const float*)d_in[7];
    const float* b_r1 = (const float*)d_in[8];
    const float* g_r1 = (const float*)d_in[9];
    const float* be_r1 = (const float*)d_in[10];
    const float* W_r2 = (const float*)d_in[11];
    const float* b_r2 = (const float*)d_in[12];
    const float* g_r2 = (const float*)d_in[13];
    const float* be_r2 = (const float*)d_in[14];
    const float* W_f  = (const float*)d_in[15];
    const float* b_f  = (const float*)d_in[16];
    const float* g_f  = (const float*)d_in[17];
    const float* be_f = (const float*)d_in[18];
    const float* W_c  = (const float*)d_in[19];
    const float* b_c  = (const float*)d_in[20];
    float* out = (float*)d_out;

    const int B = B_ROWS;

    // ---- workspace layout ----
    char* p = (char*)d_ws;
    short* preb  = (short*)p;  p += (size_t)B * H_DIM * sizeof(float);   // bf16 GEMM out
    short* fb    = (short*)p;  p += (size_t)B * H_DIM * sizeof(short);   // bf16 running residual
    char*  act   = (char*)p;   p += (size_t)B * K1_PAD;                  // fp8 A-input
    char*  A1    = act;                                                  // aliases (dead after GEMM1)
    char*  Wt_in = p;  p += (size_t)H_DIM * K1_PAD;
    char*  Wt_r1 = p;  p += (size_t)H_DIM * H_DIM;
    char*  Wt_r2 = p;  p += (size_t)H_DIM * H_DIM;
    char*  Wt_f  = p;  p += (size_t)P_DIM * H_DIM;

    // 1) prep: L2 norms + fp8 concat A1 (x16, K-interleaved)
    prep_a1<<<B, 256, 0, stream>>>(x1, x2, gf, A1);

    // 2) all weight transposes+cvt (x16, K-interleaved) in one launch
    transpose_cvt_all<<<dim3(K1_PAD / 64, H_DIM / 64, 4), 256, 0, stream>>>(
        W_in, Wt_in, W_r1, Wt_r1, W_r2, Wt_r2, W_f, Wt_f);

    // 3) input_proj GEMM + LN -> act fp8 + residual bf16
    gemm_f8<4, K1_PAD><<<dim3(B / 128, H_DIM / 256), 512, 0, stream>>>(
        A1, Wt_in, b_in, INV_G1, preb, H_DIM);
    ln_relu_f8<0, 1><<<B / 4, 256, 0, stream>>>(preb, g_in, be_in, nullptr, act, fb);

    // 4) residual block 1
    gemm_f8<4, H_DIM><<<dim3(B / 128, H_DIM / 256), 512, 0, stream>>>(
        act, Wt_r1, b_r1, INV_G, preb, H_DIM);
    ln_relu_f8<1, 1><<<B / 4, 256, 0, stream>>>(preb, g_r1, be_r1, fb, act, fb);

    // 5) residual block 2 (no bf16 residual needed after this)
    gemm_f8<4, H_DIM><<<dim3(B / 128, H_DIM / 256), 512, 0, stream>>>(
        act, Wt_r2, b_r2, INV_G, preb, H_DIM);
    ln_relu_f8<1, 0><<<B / 4, 256, 0, stream>>>(preb, g_r2, be_r2, fb, act, nullptr);

    // 6) final_proj (N=256, bf16 out, 4-wave tile -> grid 256 = 1/CU)
    gemm_f8<2, H_DIM><<<dim3(B / 128, P_DIM / 128), 256, 0, stream>>>(
        act, Wt_f, b_f, INV_G, preb, P_DIM);

    // 7) fused final LN + classifier + gender mask (wave per row)
    ln_cls<<<B / 4, 256, 0, stream>>>(preb, g_f, be_f, W_c, b_c, gf, out);
}